// Round 9
// baseline (261.013 us; speedup 1.0000x reference)
//
#include <hip/hip_runtime.h>
#include <hip/hip_fp16.h>

#define D_FEAT 128

constexpr int SCAN_BLOCK = 256;
constexpr int SCAN_ITEMS = 8;
constexpr int SCAN_CHUNK = SCAN_BLOCK * SCAN_ITEMS;

constexpr int BUCKET_SHIFT = 7;      // 128 rows per bucket
constexpr int TILE_ROWS = 1 << BUCKET_SHIFT;
constexpr int NB_MAX = 1024;
constexpr int PART_TILE = 32768;     // edges per partition block
constexpr int CAP = 6144;            // staged edges per batch (48 KB LDS)

// ---------------- fallback (round-1) atomic kernel ----------------
__global__ void __launch_bounds__(256) spmm_atomic_kernel(
    const int* __restrict__ row, const int* __restrict__ col,
    const float* __restrict__ vals, const float* __restrict__ embeds,
    float* __restrict__ out, int n_edges)
{
    const int lane = threadIdx.x & 63;
    const int wave_in_block = threadIdx.x >> 6;
    const int waves_per_block = blockDim.x >> 6;
    const int n_waves = gridDim.x * waves_per_block;
    for (int e = blockIdx.x * waves_per_block + wave_in_block; e < n_edges; e += n_waves) {
        const int r = row[e];
        const int c = col[e];
        const float v = vals[e];
        const float2 emb = *reinterpret_cast<const float2*>(&embeds[(size_t)c * D_FEAT + lane * 2]);
        float* o = &out[(size_t)r * D_FEAT + lane * 2];
        atomicAdd(o, emb.x * v);
        atomicAdd(o + 1, emb.y * v);
    }
}

// ================= fast path =================

// LDS-privatized bucket histogram (scanned mode only)
__global__ void __launch_bounds__(256) bucket_hist_kernel(
    const int* __restrict__ row, int* __restrict__ bucket_counts, int n_edges, int nb)
{
    __shared__ int cnt[NB_MAX];
    for (int b = threadIdx.x; b < nb; b += 256) cnt[b] = 0;
    __syncthreads();
    const int i = blockIdx.x * blockDim.x + threadIdx.x;
    const int stride = gridDim.x * blockDim.x;
    const int n4 = n_edges >> 2;
    for (int k = i; k < n4; k += stride) {
        int4 r4 = reinterpret_cast<const int4*>(row)[k];
        atomicAdd(&cnt[r4.x >> BUCKET_SHIFT], 1);
        atomicAdd(&cnt[r4.y >> BUCKET_SHIFT], 1);
        atomicAdd(&cnt[r4.z >> BUCKET_SHIFT], 1);
        atomicAdd(&cnt[r4.w >> BUCKET_SHIFT], 1);
    }
    for (int k = (n4 << 2) + i; k < n_edges; k += stride)
        atomicAdd(&cnt[row[k] >> BUCKET_SHIFT], 1);
    __syncthreads();
    for (int b = threadIdx.x; b < nb; b += 256) {
        int c = cnt[b];
        if (c) atomicAdd(&bucket_counts[b], c);
    }
}

// scanned mode: one block scans bucket counts -> bucket_ptr (excl) + bucket_fill
__global__ void __launch_bounds__(1024) bucket_scan_kernel(
    const int* __restrict__ bucket_counts, int* __restrict__ bucket_ptr,
    int* __restrict__ bucket_fill, int nb)
{
    __shared__ int lds[1024];
    const int t = threadIdx.x;
    lds[t] = (t < nb) ? bucket_counts[t] : 0;
    __syncthreads();
    for (int off = 1; off < 1024; off <<= 1) {
        int x = (t >= off) ? lds[t - off] : 0;
        __syncthreads();
        lds[t] += x;
        __syncthreads();
    }
    const int excl = (t == 0) ? 0 : lds[t - 1];
    if (t <= nb) bucket_ptr[t] = excl;
    if (t < nb)  bucket_fill[t] = excl;
}

// padded mode: fixed-stride bucket bases, no hist/scan needed
__global__ void __launch_bounds__(256) bucket_init_padded_kernel(
    int* __restrict__ bucket_ptr, int* __restrict__ bucket_fill, int nb, int cap_b)
{
    int b = blockIdx.x * blockDim.x + threadIdx.x;
    if (b < nb) {
        bucket_ptr[b]  = b * cap_b;
        bucket_fill[b] = b * cap_b;
    }
}

// partition edges into 128-row buckets; payload (row_local<<17 | col, half2{v,v})
__global__ void __launch_bounds__(256) partition_kernel(
    const int* __restrict__ row, const int* __restrict__ col, const float* __restrict__ vals,
    int* __restrict__ bucket_fill, uint2* __restrict__ tmp, int n_edges, int nb)
{
    __shared__ int cnt[NB_MAX];
    __shared__ int start[NB_MAX];
    const int tid = threadIdx.x;
    const int base = blockIdx.x * PART_TILE;

    for (int b = tid; b < NB_MAX; b += 256) cnt[b] = 0;
    __syncthreads();

    for (int k = 0; k < PART_TILE / 1024; ++k) {
        int idx = (base >> 2) + k * 256 + tid;          // int4 index
        if (idx * 4 + 3 < n_edges) {
            int4 r4 = reinterpret_cast<const int4*>(row)[idx];
            atomicAdd(&cnt[r4.x >> BUCKET_SHIFT], 1);
            atomicAdd(&cnt[r4.y >> BUCKET_SHIFT], 1);
            atomicAdd(&cnt[r4.z >> BUCKET_SHIFT], 1);
            atomicAdd(&cnt[r4.w >> BUCKET_SHIFT], 1);
        } else {
            for (int j = 0; j < 4; ++j) {
                int e = idx * 4 + j;
                if (e < n_edges) atomicAdd(&cnt[row[e] >> BUCKET_SHIFT], 1);
            }
        }
    }
    __syncthreads();

    for (int b = tid; b < nb; b += 256) {
        int c = cnt[b];
        if (c > 0) start[b] = atomicAdd(&bucket_fill[b], c);
    }
    __syncthreads();

    for (int k = 0; k < PART_TILE / 256; ++k) {
        int e = base + k * 256 + tid;
        if (e < n_edges) {
            int r = row[e];
            int b = r >> BUCKET_SHIFT;
            int slot = atomicSub(&cnt[b], 1) - 1;
            unsigned hb = (unsigned)__half_as_ushort(__float2half(vals[e]));
            uint2 p;
            p.x = ((unsigned)(r & (TILE_ROWS - 1)) << 17) | (unsigned)col[e];
            p.y = hb | (hb << 16);
            tmp[start[b] + slot] = p;
        }
    }
}

// ---------------- embeds f32 -> f16 ----------------
__global__ void __launch_bounds__(256) convert_kernel(
    const float* __restrict__ embeds, unsigned short* __restrict__ out16, int n4)
{
    int i = blockIdx.x * blockDim.x + threadIdx.x;
    int stride = gridDim.x * blockDim.x;
    for (; i < n4; i += stride) {
        float4 f = *reinterpret_cast<const float4*>(&embeds[(size_t)i * 4]);
        ushort4 o;
        o.x = __half_as_ushort(__float2half(f.x));
        o.y = __half_as_ushort(__float2half(f.y));
        o.z = __half_as_ushort(__float2half(f.z));
        o.w = __half_as_ushort(__float2half(f.w));
        *reinterpret_cast<ushort4*>(&out16[(size_t)i * 4]) = o;
    }
}

__device__ __forceinline__ __half2 u2h2(unsigned u)
{
    return *reinterpret_cast<__half2*>(&u);
}

// ---------------- fused sort+SpMM: LDS row-sort, half-wave dwordx2, pk_fma_f16 ----
// 1024 threads / 16 waves per 128-row bucket. Wave owns 8 rows; lanes 0-31
// process even edges, 32-63 odd edges; lane loads 8B (4 f16 feats); math is
// v_pk_fma_f16 (2 feats/instr, no unpack). Halves merged via shfl at the end.
__global__ void __launch_bounds__(1024, 8) spmm_bucket_sorted_kernel(
    const uint2* __restrict__ tmp, const int* __restrict__ bucket_ptr,
    const int* __restrict__ bucket_fill,
    const unsigned short* __restrict__ embeds16, float* __restrict__ out, int n_nodes)
{
    __shared__ uint2 sedge[CAP];          // 48 KB
    __shared__ int cnt[TILE_ROWS];
    __shared__ int rstart[TILE_ROWS];
    __shared__ int rcur[TILE_ROWS];
    __shared__ int sscan[TILE_ROWS];

    const int b = blockIdx.x;
    const int lo = bucket_ptr[b];
    const int hi = bucket_fill[b];        // final fill = base + count (both modes)
    const int t = threadIdx.x;
    const int lane = t & 63;
    const int h = lane >> 5;              // half-wave id (0/1)
    const int lq = lane & 31;             // lane within half; owns feats lq*4..+3
    const int w = t >> 6;                 // wave 0..15, owns rows 8w..8w+7

    __half2 acc[16];                      // [2*rr] = feats lq*4..+1, [2*rr+1] = +2..+3
    #pragma unroll
    for (int i = 0; i < 16; ++i) acc[i] = __float2half2_rn(0.f);

    for (int cur = lo; cur < hi; cur += CAP) {
        const int bcount = min(CAP, hi - cur);

        // stage edges into registers (coalesced), CAP/1024 = 6 per thread
        uint2 e[6];
        #pragma unroll
        for (int k = 0; k < 6; ++k) {
            int idx = t + k * 1024;
            if (idx < bcount) e[k] = tmp[cur + idx];
        }
        if (t < TILE_ROWS) { cnt[t] = 0; rcur[t] = 0; }
        __syncthreads();

        // per-row count (int LDS atomics)
        #pragma unroll
        for (int k = 0; k < 6; ++k) {
            int idx = t + k * 1024;
            if (idx < bcount) atomicAdd(&cnt[(e[k].x >> 17) & (TILE_ROWS - 1)], 1);
        }
        __syncthreads();

        // exclusive scan of cnt[128] -> rstart
        if (t < TILE_ROWS) sscan[t] = cnt[t];
        __syncthreads();
        for (int off = 1; off < TILE_ROWS; off <<= 1) {
            int v = 0;
            if (t < TILE_ROWS && t >= off) v = sscan[t - off];
            __syncthreads();
            if (t < TILE_ROWS) sscan[t] += v;
            __syncthreads();
        }
        if (t < TILE_ROWS) rstart[t] = sscan[t] - cnt[t];
        __syncthreads();

        // scatter row-sorted into sedge
        #pragma unroll
        for (int k = 0; k < 6; ++k) {
            int idx = t + k * 1024;
            if (idx < bcount) {
                int rl = (e[k].x >> 17) & (TILE_ROWS - 1);
                int pos = rstart[rl] + atomicAdd(&rcur[rl], 1);
                sedge[pos] = uint2{e[k].x & 0x1FFFFu, e[k].y};
            }
        }
        __syncthreads();

        // consume: wave w accumulates its 8 rows; halves take alternating edges
        #pragma unroll
        for (int rr = 0; rr < 8; ++rr) {
            const int r = w * 8 + rr;
            const int js = rstart[r];
            const int je = js + cnt[r];
            int j = js;
            for (; j + 7 < je; j += 8) {
                uint2 q0 = sedge[j + 0 + h];
                uint2 q1 = sedge[j + 2 + h];
                uint2 q2 = sedge[j + 4 + h];
                uint2 q3 = sedge[j + 6 + h];
                uint2 u0 = *reinterpret_cast<const uint2*>(&embeds16[((size_t)q0.x << 7) + lq * 4]);
                uint2 u1 = *reinterpret_cast<const uint2*>(&embeds16[((size_t)q1.x << 7) + lq * 4]);
                uint2 u2 = *reinterpret_cast<const uint2*>(&embeds16[((size_t)q2.x << 7) + lq * 4]);
                uint2 u3 = *reinterpret_cast<const uint2*>(&embeds16[((size_t)q3.x << 7) + lq * 4]);
                acc[2*rr]   = __hfma2(u2h2(q0.y), u2h2(u0.x), acc[2*rr]);
                acc[2*rr+1] = __hfma2(u2h2(q0.y), u2h2(u0.y), acc[2*rr+1]);
                acc[2*rr]   = __hfma2(u2h2(q1.y), u2h2(u1.x), acc[2*rr]);
                acc[2*rr+1] = __hfma2(u2h2(q1.y), u2h2(u1.y), acc[2*rr+1]);
                acc[2*rr]   = __hfma2(u2h2(q2.y), u2h2(u2.x), acc[2*rr]);
                acc[2*rr+1] = __hfma2(u2h2(q2.y), u2h2(u2.y), acc[2*rr+1]);
                acc[2*rr]   = __hfma2(u2h2(q3.y), u2h2(u3.x), acc[2*rr]);
                acc[2*rr+1] = __hfma2(u2h2(q3.y), u2h2(u3.y), acc[2*rr+1]);
            }
            for (; j + 1 < je; j += 2) {
                uint2 q = sedge[j + h];
                uint2 u = *reinterpret_cast<const uint2*>(&embeds16[((size_t)q.x << 7) + lq * 4]);
                acc[2*rr]   = __hfma2(u2h2(q.y), u2h2(u.x), acc[2*rr]);
                acc[2*rr+1] = __hfma2(u2h2(q.y), u2h2(u.y), acc[2*rr+1]);
            }
            if (j < je && h == 0) {      // single leftover edge: half 0 only
                uint2 q = sedge[j];
                uint2 u = *reinterpret_cast<const uint2*>(&embeds16[((size_t)q.x << 7) + lq * 4]);
                acc[2*rr]   = __hfma2(u2h2(q.y), u2h2(u.x), acc[2*rr]);
                acc[2*rr+1] = __hfma2(u2h2(q.y), u2h2(u.y), acc[2*rr+1]);
            }
        }
        __syncthreads();   // protect sedge before next batch
    }

    // convert to f32, merge halves (disjoint edge subsets), write
    float4 facc[8];
    #pragma unroll
    for (int rr = 0; rr < 8; ++rr) {
        float2 a = __half22float2(acc[2*rr]);
        float2 bq = __half22float2(acc[2*rr+1]);
        facc[rr] = float4{a.x, a.y, bq.x, bq.y};
        facc[rr].x += __shfl_xor(facc[rr].x, 32);
        facc[rr].y += __shfl_xor(facc[rr].y, 32);
        facc[rr].z += __shfl_xor(facc[rr].z, 32);
        facc[rr].w += __shfl_xor(facc[rr].w, 32);
    }

    // half h writes rows w*8 + k + 4h (static indices + cndmask select)
    const int rbase = b << BUCKET_SHIFT;
    #pragma unroll
    for (int k = 0; k < 4; ++k) {
        float4 a0 = facc[k];
        float4 a1 = facc[k + 4];
        float4 vv;
        vv.x = h ? a1.x : a0.x;
        vv.y = h ? a1.y : a0.y;
        vv.z = h ? a1.z : a0.z;
        vv.w = h ? a1.w : a0.w;
        int r = rbase + w * 8 + k + 4 * h;
        if (r < n_nodes)
            *reinterpret_cast<float4*>(&out[(size_t)r * D_FEAT + lq * 4]) = vv;
    }
}

// ================= round-2 fallback pieces =================
__global__ void hist_kernel(const int* __restrict__ row, int* __restrict__ counts, int n)
{
    int i = blockIdx.x * blockDim.x + threadIdx.x;
    int stride = gridDim.x * blockDim.x;
    for (; i < n; i += stride) atomicAdd(&counts[row[i]], 1);
}

__global__ void __launch_bounds__(SCAN_BLOCK) scan1_kernel(
    const int* __restrict__ counts, int* __restrict__ scan_out,
    int* __restrict__ chunk_sums, int n)
{
    __shared__ int lds[SCAN_BLOCK];
    const int chunk = blockIdx.x;
    const int base = chunk * SCAN_CHUNK;
    const int tbase = base + threadIdx.x * SCAN_ITEMS;

    int pref[SCAN_ITEMS];
    int tsum = 0;
    for (int k = 0; k < SCAN_ITEMS; ++k) {
        int idx = tbase + k;
        int v = (idx < n) ? counts[idx] : 0;
        pref[k] = tsum;
        tsum += v;
    }
    lds[threadIdx.x] = tsum;
    __syncthreads();
    for (int off = 1; off < SCAN_BLOCK; off <<= 1) {
        int v = (threadIdx.x >= off) ? lds[threadIdx.x - off] : 0;
        __syncthreads();
        lds[threadIdx.x] += v;
        __syncthreads();
    }
    const int texcl = (threadIdx.x == 0) ? 0 : lds[threadIdx.x - 1];
    for (int k = 0; k < SCAN_ITEMS; ++k) {
        int idx = tbase + k;
        if (idx < n) scan_out[idx] = texcl + pref[k];
    }
    if (threadIdx.x == SCAN_BLOCK - 1) chunk_sums[chunk] = lds[SCAN_BLOCK - 1];
}

__global__ void scan2_kernel(int* chunk_sums, int nchunks)
{
    if (blockIdx.x == 0 && threadIdx.x == 0) {
        int acc = 0;
        for (int i = 0; i < nchunks; ++i) { int v = chunk_sums[i]; chunk_sums[i] = acc; acc += v; }
    }
}

__global__ void scan3_kernel(int* __restrict__ row_ptr, const int* __restrict__ chunk_sums,
                             int n, int n_edges)
{
    int i = blockIdx.x * blockDim.x + threadIdx.x;
    if (i < n) row_ptr[i] += chunk_sums[i / SCAN_CHUNK];
    if (i == 0) row_ptr[n] = n_edges;
}

__global__ void scatter_kernel(const int* __restrict__ row, const int* __restrict__ col,
                               const float* __restrict__ vals,
                               const int* __restrict__ row_ptr, int* __restrict__ row_fill,
                               uint2* __restrict__ sorted_cv, int n_edges)
{
    int i = blockIdx.x * blockDim.x + threadIdx.x;
    int stride = gridDim.x * blockDim.x;
    for (; i < n_edges; i += stride) {
        int r = row[i];
        int pos = row_ptr[r] + atomicAdd(&row_fill[r], 1);
        uint2 cv;
        cv.x = (unsigned)col[i];
        cv.y = __float_as_uint(vals[i]);
        sorted_cv[pos] = cv;
    }
}

__global__ void __launch_bounds__(256) spmm_csr_kernel(
    const int* __restrict__ row_ptr, const uint2* __restrict__ sorted_cv,
    const float* __restrict__ embeds, float* __restrict__ out, int n_rows)
{
    const int lane = threadIdx.x & 63;
    const int wid = (blockIdx.x * blockDim.x + threadIdx.x) >> 6;
    const int n_waves = (gridDim.x * blockDim.x) >> 6;

    for (int r = wid; r < n_rows; r += n_waves) {
        const int start = row_ptr[r];
        const int end   = row_ptr[r + 1];
        float2 acc = {0.f, 0.f};
        for (int j = start; j < end; ++j) {
            uint2 cv = sorted_cv[j];
            const float2 e = *reinterpret_cast<const float2*>(&embeds[(size_t)cv.x * D_FEAT + lane * 2]);
            const float v = __uint_as_float(cv.y);
            acc.x += v * e.x;
            acc.y += v * e.y;
        }
        *reinterpret_cast<float2*>(&out[(size_t)r * D_FEAT + lane * 2]) = acc;
    }
}

extern "C" void kernel_launch(void* const* d_in, const int* in_sizes, int n_in,
                              void* d_out, int out_size, void* d_ws, size_t ws_size,
                              hipStream_t stream) {
    const int*   row    = (const int*)d_in[0];
    const int*   col    = (const int*)d_in[1];
    const float* vals   = (const float*)d_in[2];
    const float* embeds = (const float*)d_in[3];
    float*       out    = (float*)d_out;

    const int n_edges = in_sizes[0];
    const int n_nodes = in_sizes[3] / D_FEAT;
    const int nchunks = (n_nodes + SCAN_CHUNK - 1) / SCAN_CHUNK;
    const int nb = (n_nodes + TILE_ROWS - 1) >> BUCKET_SHIFT;

    // padded bucket stride: avg + 25% + 256 (>=16 sigma for Binomial bucket sizes)
    const int avg = n_edges / (nb > 0 ? nb : 1);
    const int cap_b = avg + avg / 4 + 256;

    char* base = (char*)d_ws;

    // padded layout (no hist/scan)
    size_t offP = 0;
    uint2* tmpP           = (uint2*)(base + offP);             offP += ((size_t)nb * cap_b * 8 + 255) & ~(size_t)255;
    unsigned short* emb16P = (unsigned short*)(base + offP);   offP += ((size_t)n_nodes * D_FEAT * 2 + 255) & ~(size_t)255;
    int* bptrP            = (int*)(base + offP);               offP += (size_t)(nb + 1) * 4;
    int* bfillP           = (int*)(base + offP);               offP += (size_t)(nb + 1) * 4;

    // scanned layout (exact tmp)
    size_t offS = 0;
    uint2* tmpS           = (uint2*)(base + offS);             offS += ((size_t)n_edges * 8 + 255) & ~(size_t)255;
    unsigned short* emb16S = (unsigned short*)(base + offS);   offS += ((size_t)n_nodes * D_FEAT * 2 + 255) & ~(size_t)255;
    int* bcntS            = (int*)(base + offS);               offS += (size_t)(nb + 1) * 4;
    int* bptrS            = (int*)(base + offS);               offS += (size_t)(nb + 1) * 4;
    int* bfillS           = (int*)(base + offS);               offS += (size_t)(nb + 1) * 4;

    const bool common_ok = (nb <= 1023) && (n_nodes < (1 << 17));
    const bool padded_ok  = common_ok && (offP <= ws_size);
    const bool scanned_ok = common_ok && (offS <= ws_size);

    if (!padded_ok && !scanned_ok) {
        // round-2 fallback layout
        size_t off2 = 0;
        uint2* s_cv = (uint2*)(base + off2); off2 += (size_t)n_edges * 8;
        int* rc  = (int*)(base + off2); off2 += (size_t)n_nodes * 4;
        int* rf  = (int*)(base + off2); off2 += (size_t)n_nodes * 4;
        int* rp  = (int*)(base + off2); off2 += (size_t)(n_nodes + 1) * 4;
        int* cs  = (int*)(base + off2); off2 += (size_t)nchunks * 4;
        if (off2 > ws_size) {
            hipMemsetAsync(d_out, 0, (size_t)out_size * sizeof(float), stream);
            spmm_atomic_kernel<<<2048, 256, 0, stream>>>(row, col, vals, embeds, out, n_edges);
            return;
        }
        hipMemsetAsync(rc, 0, (size_t)n_nodes * 2 * sizeof(int), stream);
        hist_kernel<<<2048, 256, 0, stream>>>(row, rc, n_edges);
        scan1_kernel<<<nchunks, SCAN_BLOCK, 0, stream>>>(rc, rp, cs, n_nodes);
        scan2_kernel<<<1, 64, 0, stream>>>(cs, nchunks);
        scan3_kernel<<<(n_nodes + 256) / 256, 256, 0, stream>>>(rp, cs, n_nodes, n_edges);
        scatter_kernel<<<2048, 256, 0, stream>>>(row, col, vals, rp, rf, s_cv, n_edges);
        spmm_csr_kernel<<<4096, 256, 0, stream>>>(rp, s_cv, embeds, out, n_nodes);
        return;
    }

    uint2* tmp;
    unsigned short* embeds16;
    int *bptr, *bfill;

    const int part_blocks = (n_edges + PART_TILE - 1) / PART_TILE;

    if (padded_ok) {
        tmp = tmpP; embeds16 = emb16P; bptr = bptrP; bfill = bfillP;
        bucket_init_padded_kernel<<<(nb + 255) / 256, 256, 0, stream>>>(bptr, bfill, nb, cap_b);
    } else {
        tmp = tmpS; embeds16 = emb16S; bptr = bptrS; bfill = bfillS;
        hipMemsetAsync(bcntS, 0, (size_t)(nb + 1) * sizeof(int), stream);
        bucket_hist_kernel<<<512, 256, 0, stream>>>(row, bcntS, n_edges, nb);
        bucket_scan_kernel<<<1, 1024, 0, stream>>>(bcntS, bptr, bfill, nb);
    }

    partition_kernel<<<part_blocks, 256, 0, stream>>>(row, col, vals, bfill, tmp, n_edges, nb);

    const int n4 = n_nodes * D_FEAT / 4;
    convert_kernel<<<4096, 256, 0, stream>>>(embeds, embeds16, n4);

    spmm_bucket_sorted_kernel<<<nb, 1024, 0, stream>>>(tmp, bptr, bfill, embeds16, out, n_nodes);
}

// Round 10
// 232.887 us; speedup vs baseline: 1.1208x; 1.1208x over previous
//
#include <hip/hip_runtime.h>
#include <hip/hip_fp16.h>

#define D_FEAT 128

constexpr int SCAN_BLOCK = 256;
constexpr int SCAN_ITEMS = 8;
constexpr int SCAN_CHUNK = SCAN_BLOCK * SCAN_ITEMS;

constexpr int BUCKET_SHIFT = 7;      // 128 rows per bucket
constexpr int TILE_ROWS = 1 << BUCKET_SHIFT;
constexpr int NB_MAX = 1024;
constexpr int PART_TILE = 4096;      // edges per partition block (782 blocks @ 3.2M)
constexpr int CAP = 6144;            // staged edges per batch (48 KB LDS)

// ---------------- fallback (round-1) atomic kernel ----------------
__global__ void __launch_bounds__(256) spmm_atomic_kernel(
    const int* __restrict__ row, const int* __restrict__ col,
    const float* __restrict__ vals, const float* __restrict__ embeds,
    float* __restrict__ out, int n_edges)
{
    const int lane = threadIdx.x & 63;
    const int wave_in_block = threadIdx.x >> 6;
    const int waves_per_block = blockDim.x >> 6;
    const int n_waves = gridDim.x * waves_per_block;
    for (int e = blockIdx.x * waves_per_block + wave_in_block; e < n_edges; e += n_waves) {
        const int r = row[e];
        const int c = col[e];
        const float v = vals[e];
        const float2 emb = *reinterpret_cast<const float2*>(&embeds[(size_t)c * D_FEAT + lane * 2]);
        float* o = &out[(size_t)r * D_FEAT + lane * 2];
        atomicAdd(o, emb.x * v);
        atomicAdd(o + 1, emb.y * v);
    }
}

// ================= fast path =================

// LDS-privatized bucket histogram (scanned mode only)
__global__ void __launch_bounds__(256) bucket_hist_kernel(
    const int* __restrict__ row, int* __restrict__ bucket_counts, int n_edges, int nb)
{
    __shared__ int cnt[NB_MAX];
    for (int b = threadIdx.x; b < nb; b += 256) cnt[b] = 0;
    __syncthreads();
    const int i = blockIdx.x * blockDim.x + threadIdx.x;
    const int stride = gridDim.x * blockDim.x;
    const int n4 = n_edges >> 2;
    for (int k = i; k < n4; k += stride) {
        int4 r4 = reinterpret_cast<const int4*>(row)[k];
        atomicAdd(&cnt[r4.x >> BUCKET_SHIFT], 1);
        atomicAdd(&cnt[r4.y >> BUCKET_SHIFT], 1);
        atomicAdd(&cnt[r4.z >> BUCKET_SHIFT], 1);
        atomicAdd(&cnt[r4.w >> BUCKET_SHIFT], 1);
    }
    for (int k = (n4 << 2) + i; k < n_edges; k += stride)
        atomicAdd(&cnt[row[k] >> BUCKET_SHIFT], 1);
    __syncthreads();
    for (int b = threadIdx.x; b < nb; b += 256) {
        int c = cnt[b];
        if (c) atomicAdd(&bucket_counts[b], c);
    }
}

// scanned mode: one block scans bucket counts -> bucket_ptr (excl) + bucket_fill
__global__ void __launch_bounds__(1024) bucket_scan_kernel(
    const int* __restrict__ bucket_counts, int* __restrict__ bucket_ptr,
    int* __restrict__ bucket_fill, int nb)
{
    __shared__ int lds[1024];
    const int t = threadIdx.x;
    lds[t] = (t < nb) ? bucket_counts[t] : 0;
    __syncthreads();
    for (int off = 1; off < 1024; off <<= 1) {
        int x = (t >= off) ? lds[t - off] : 0;
        __syncthreads();
        lds[t] += x;
        __syncthreads();
    }
    const int excl = (t == 0) ? 0 : lds[t - 1];
    if (t <= nb) bucket_ptr[t] = excl;
    if (t < nb)  bucket_fill[t] = excl;
}

// padded mode: fixed-stride bucket bases, no hist/scan needed
__global__ void __launch_bounds__(256) bucket_init_padded_kernel(
    int* __restrict__ bucket_ptr, int* __restrict__ bucket_fill, int nb, int cap_b)
{
    int b = blockIdx.x * blockDim.x + threadIdx.x;
    if (b < nb) {
        bucket_ptr[b]  = b * cap_b;
        bucket_fill[b] = b * cap_b;
    }
}

// partition edges into 128-row buckets; payload (row_local<<17 | col, half2{v,v})
__global__ void __launch_bounds__(256) partition_kernel(
    const int* __restrict__ row, const int* __restrict__ col, const float* __restrict__ vals,
    int* __restrict__ bucket_fill, uint2* __restrict__ tmp, int n_edges, int nb)
{
    __shared__ int cnt[NB_MAX];
    __shared__ int start[NB_MAX];
    const int tid = threadIdx.x;
    const int base = blockIdx.x * PART_TILE;

    for (int b = tid; b < NB_MAX; b += 256) cnt[b] = 0;
    __syncthreads();

    // count pass, int4-vectorized (PART_TILE multiple of 1024)
    #pragma unroll
    for (int k = 0; k < PART_TILE / 1024; ++k) {
        int idx = (base >> 2) + k * 256 + tid;          // int4 index
        if (idx * 4 + 3 < n_edges) {
            int4 r4 = reinterpret_cast<const int4*>(row)[idx];
            atomicAdd(&cnt[r4.x >> BUCKET_SHIFT], 1);
            atomicAdd(&cnt[r4.y >> BUCKET_SHIFT], 1);
            atomicAdd(&cnt[r4.z >> BUCKET_SHIFT], 1);
            atomicAdd(&cnt[r4.w >> BUCKET_SHIFT], 1);
        } else {
            for (int j = 0; j < 4; ++j) {
                int e = idx * 4 + j;
                if (e < n_edges) atomicAdd(&cnt[row[e] >> BUCKET_SHIFT], 1);
            }
        }
    }
    __syncthreads();

    for (int b = tid; b < nb; b += 256) {
        int c = cnt[b];
        if (c > 0) start[b] = atomicAdd(&bucket_fill[b], c);
    }
    __syncthreads();

    // scatter pass, also int4/float4-vectorized
    #pragma unroll
    for (int k = 0; k < PART_TILE / 1024; ++k) {
        int idx = (base >> 2) + k * 256 + tid;
        if (idx * 4 + 3 < n_edges) {
            int4  r4 = reinterpret_cast<const int4*>(row)[idx];
            int4  c4 = reinterpret_cast<const int4*>(col)[idx];
            float4 v4 = reinterpret_cast<const float4*>(vals)[idx];
            const int rs[4]   = {r4.x, r4.y, r4.z, r4.w};
            const int cs[4]   = {c4.x, c4.y, c4.z, c4.w};
            const float vs[4] = {v4.x, v4.y, v4.z, v4.w};
            #pragma unroll
            for (int j = 0; j < 4; ++j) {
                int r = rs[j];
                int b = r >> BUCKET_SHIFT;
                int slot = atomicSub(&cnt[b], 1) - 1;
                unsigned hb = (unsigned)__half_as_ushort(__float2half(vs[j]));
                uint2 p;
                p.x = ((unsigned)(r & (TILE_ROWS - 1)) << 17) | (unsigned)cs[j];
                p.y = hb | (hb << 16);
                tmp[start[b] + slot] = p;
            }
        } else {
            for (int j = 0; j < 4; ++j) {
                int e = idx * 4 + j;
                if (e < n_edges) {
                    int r = row[e];
                    int b = r >> BUCKET_SHIFT;
                    int slot = atomicSub(&cnt[b], 1) - 1;
                    unsigned hb = (unsigned)__half_as_ushort(__float2half(vals[e]));
                    uint2 p;
                    p.x = ((unsigned)(r & (TILE_ROWS - 1)) << 17) | (unsigned)col[e];
                    p.y = hb | (hb << 16);
                    tmp[start[b] + slot] = p;
                }
            }
        }
    }
}

// ---------------- embeds f32 -> f16 ----------------
__global__ void __launch_bounds__(256) convert_kernel(
    const float* __restrict__ embeds, unsigned short* __restrict__ out16, int n4)
{
    int i = blockIdx.x * blockDim.x + threadIdx.x;
    int stride = gridDim.x * blockDim.x;
    for (; i < n4; i += stride) {
        float4 f = *reinterpret_cast<const float4*>(&embeds[(size_t)i * 4]);
        ushort4 o;
        o.x = __half_as_ushort(__float2half(f.x));
        o.y = __half_as_ushort(__float2half(f.y));
        o.z = __half_as_ushort(__float2half(f.z));
        o.w = __half_as_ushort(__float2half(f.w));
        *reinterpret_cast<ushort4*>(&out16[(size_t)i * 4]) = o;
    }
}

__device__ __forceinline__ __half2 u2h2(unsigned u)
{
    return *reinterpret_cast<__half2*>(&u);
}

// ---------------- fused sort+SpMM: LDS row-sort, half-wave dwordx2, pk_fma_f16 ----
__global__ void __launch_bounds__(1024, 8) spmm_bucket_sorted_kernel(
    const uint2* __restrict__ tmp, const int* __restrict__ bucket_ptr,
    const int* __restrict__ bucket_fill,
    const unsigned short* __restrict__ embeds16, float* __restrict__ out, int n_nodes)
{
    __shared__ uint2 sedge[CAP];          // 48 KB
    __shared__ int cnt[TILE_ROWS];
    __shared__ int rstart[TILE_ROWS];
    __shared__ int rcur[TILE_ROWS];
    __shared__ int sscan[TILE_ROWS];

    const int b = blockIdx.x;
    const int lo = bucket_ptr[b];
    const int hi = bucket_fill[b];        // final fill = base + count (both modes)
    const int t = threadIdx.x;
    const int lane = t & 63;
    const int h = lane >> 5;              // half-wave id (0/1)
    const int lq = lane & 31;             // lane within half; owns feats lq*4..+3
    const int w = t >> 6;                 // wave 0..15, owns rows 8w..8w+7

    __half2 acc[16];                      // [2*rr] = feats lq*4..+1, [2*rr+1] = +2..+3
    #pragma unroll
    for (int i = 0; i < 16; ++i) acc[i] = __float2half2_rn(0.f);

    for (int cur = lo; cur < hi; cur += CAP) {
        const int bcount = min(CAP, hi - cur);

        // stage edges into registers (coalesced), CAP/1024 = 6 per thread
        uint2 e[6];
        #pragma unroll
        for (int k = 0; k < 6; ++k) {
            int idx = t + k * 1024;
            if (idx < bcount) e[k] = tmp[cur + idx];
        }
        if (t < TILE_ROWS) { cnt[t] = 0; rcur[t] = 0; }
        __syncthreads();

        // per-row count (int LDS atomics)
        #pragma unroll
        for (int k = 0; k < 6; ++k) {
            int idx = t + k * 1024;
            if (idx < bcount) atomicAdd(&cnt[(e[k].x >> 17) & (TILE_ROWS - 1)], 1);
        }
        __syncthreads();

        // exclusive scan of cnt[128] -> rstart
        if (t < TILE_ROWS) sscan[t] = cnt[t];
        __syncthreads();
        for (int off = 1; off < TILE_ROWS; off <<= 1) {
            int v = 0;
            if (t < TILE_ROWS && t >= off) v = sscan[t - off];
            __syncthreads();
            if (t < TILE_ROWS) sscan[t] += v;
            __syncthreads();
        }
        if (t < TILE_ROWS) rstart[t] = sscan[t] - cnt[t];
        __syncthreads();

        // scatter row-sorted into sedge
        #pragma unroll
        for (int k = 0; k < 6; ++k) {
            int idx = t + k * 1024;
            if (idx < bcount) {
                int rl = (e[k].x >> 17) & (TILE_ROWS - 1);
                int pos = rstart[rl] + atomicAdd(&rcur[rl], 1);
                sedge[pos] = uint2{e[k].x & 0x1FFFFu, e[k].y};
            }
        }
        __syncthreads();

        // consume: wave w accumulates its 8 rows; halves take alternating edges
        #pragma unroll
        for (int rr = 0; rr < 8; ++rr) {
            const int r = w * 8 + rr;
            const int js = rstart[r];
            const int je = js + cnt[r];
            int j = js;
            for (; j + 7 < je; j += 8) {
                uint2 q0 = sedge[j + 0 + h];
                uint2 q1 = sedge[j + 2 + h];
                uint2 q2 = sedge[j + 4 + h];
                uint2 q3 = sedge[j + 6 + h];
                uint2 u0 = *reinterpret_cast<const uint2*>(&embeds16[((size_t)q0.x << 7) + lq * 4]);
                uint2 u1 = *reinterpret_cast<const uint2*>(&embeds16[((size_t)q1.x << 7) + lq * 4]);
                uint2 u2 = *reinterpret_cast<const uint2*>(&embeds16[((size_t)q2.x << 7) + lq * 4]);
                uint2 u3 = *reinterpret_cast<const uint2*>(&embeds16[((size_t)q3.x << 7) + lq * 4]);
                acc[2*rr]   = __hfma2(u2h2(q0.y), u2h2(u0.x), acc[2*rr]);
                acc[2*rr+1] = __hfma2(u2h2(q0.y), u2h2(u0.y), acc[2*rr+1]);
                acc[2*rr]   = __hfma2(u2h2(q1.y), u2h2(u1.x), acc[2*rr]);
                acc[2*rr+1] = __hfma2(u2h2(q1.y), u2h2(u1.y), acc[2*rr+1]);
                acc[2*rr]   = __hfma2(u2h2(q2.y), u2h2(u2.x), acc[2*rr]);
                acc[2*rr+1] = __hfma2(u2h2(q2.y), u2h2(u2.y), acc[2*rr+1]);
                acc[2*rr]   = __hfma2(u2h2(q3.y), u2h2(u3.x), acc[2*rr]);
                acc[2*rr+1] = __hfma2(u2h2(q3.y), u2h2(u3.y), acc[2*rr+1]);
            }
            for (; j + 1 < je; j += 2) {
                uint2 q = sedge[j + h];
                uint2 u = *reinterpret_cast<const uint2*>(&embeds16[((size_t)q.x << 7) + lq * 4]);
                acc[2*rr]   = __hfma2(u2h2(q.y), u2h2(u.x), acc[2*rr]);
                acc[2*rr+1] = __hfma2(u2h2(q.y), u2h2(u.y), acc[2*rr+1]);
            }
            if (j < je && h == 0) {      // single leftover edge: half 0 only
                uint2 q = sedge[j];
                uint2 u = *reinterpret_cast<const uint2*>(&embeds16[((size_t)q.x << 7) + lq * 4]);
                acc[2*rr]   = __hfma2(u2h2(q.y), u2h2(u.x), acc[2*rr]);
                acc[2*rr+1] = __hfma2(u2h2(q.y), u2h2(u.y), acc[2*rr+1]);
            }
        }
        __syncthreads();   // protect sedge before next batch
    }

    // convert to f32, merge halves (disjoint edge subsets), write
    float4 facc[8];
    #pragma unroll
    for (int rr = 0; rr < 8; ++rr) {
        float2 a = __half22float2(acc[2*rr]);
        float2 bq = __half22float2(acc[2*rr+1]);
        facc[rr] = float4{a.x, a.y, bq.x, bq.y};
        facc[rr].x += __shfl_xor(facc[rr].x, 32);
        facc[rr].y += __shfl_xor(facc[rr].y, 32);
        facc[rr].z += __shfl_xor(facc[rr].z, 32);
        facc[rr].w += __shfl_xor(facc[rr].w, 32);
    }

    // half h writes rows w*8 + k + 4h (static indices + cndmask select)
    const int rbase = b << BUCKET_SHIFT;
    #pragma unroll
    for (int k = 0; k < 4; ++k) {
        float4 a0 = facc[k];
        float4 a1 = facc[k + 4];
        float4 vv;
        vv.x = h ? a1.x : a0.x;
        vv.y = h ? a1.y : a0.y;
        vv.z = h ? a1.z : a0.z;
        vv.w = h ? a1.w : a0.w;
        int r = rbase + w * 8 + k + 4 * h;
        if (r < n_nodes)
            *reinterpret_cast<float4*>(&out[(size_t)r * D_FEAT + lq * 4]) = vv;
    }
}

// ================= round-2 fallback pieces =================
__global__ void hist_kernel(const int* __restrict__ row, int* __restrict__ counts, int n)
{
    int i = blockIdx.x * blockDim.x + threadIdx.x;
    int stride = gridDim.x * blockDim.x;
    for (; i < n; i += stride) atomicAdd(&counts[row[i]], 1);
}

__global__ void __launch_bounds__(SCAN_BLOCK) scan1_kernel(
    const int* __restrict__ counts, int* __restrict__ scan_out,
    int* __restrict__ chunk_sums, int n)
{
    __shared__ int lds[SCAN_BLOCK];
    const int chunk = blockIdx.x;
    const int base = chunk * SCAN_CHUNK;
    const int tbase = base + threadIdx.x * SCAN_ITEMS;

    int pref[SCAN_ITEMS];
    int tsum = 0;
    for (int k = 0; k < SCAN_ITEMS; ++k) {
        int idx = tbase + k;
        int v = (idx < n) ? counts[idx] : 0;
        pref[k] = tsum;
        tsum += v;
    }
    lds[threadIdx.x] = tsum;
    __syncthreads();
    for (int off = 1; off < SCAN_BLOCK; off <<= 1) {
        int v = (threadIdx.x >= off) ? lds[threadIdx.x - off] : 0;
        __syncthreads();
        lds[threadIdx.x] += v;
        __syncthreads();
    }
    const int texcl = (threadIdx.x == 0) ? 0 : lds[threadIdx.x - 1];
    for (int k = 0; k < SCAN_ITEMS; ++k) {
        int idx = tbase + k;
        if (idx < n) scan_out[idx] = texcl + pref[k];
    }
    if (threadIdx.x == SCAN_BLOCK - 1) chunk_sums[chunk] = lds[SCAN_BLOCK - 1];
}

__global__ void scan2_kernel(int* chunk_sums, int nchunks)
{
    if (blockIdx.x == 0 && threadIdx.x == 0) {
        int acc = 0;
        for (int i = 0; i < nchunks; ++i) { int v = chunk_sums[i]; chunk_sums[i] = acc; acc += v; }
    }
}

__global__ void scan3_kernel(int* __restrict__ row_ptr, const int* __restrict__ chunk_sums,
                             int n, int n_edges)
{
    int i = blockIdx.x * blockDim.x + threadIdx.x;
    if (i < n) row_ptr[i] += chunk_sums[i / SCAN_CHUNK];
    if (i == 0) row_ptr[n] = n_edges;
}

__global__ void scatter_kernel(const int* __restrict__ row, const int* __restrict__ col,
                               const float* __restrict__ vals,
                               const int* __restrict__ row_ptr, int* __restrict__ row_fill,
                               uint2* __restrict__ sorted_cv, int n_edges)
{
    int i = blockIdx.x * blockDim.x + threadIdx.x;
    int stride = gridDim.x * blockDim.x;
    for (; i < n_edges; i += stride) {
        int r = row[i];
        int pos = row_ptr[r] + atomicAdd(&row_fill[r], 1);
        uint2 cv;
        cv.x = (unsigned)col[i];
        cv.y = __float_as_uint(vals[i]);
        sorted_cv[pos] = cv;
    }
}

__global__ void __launch_bounds__(256) spmm_csr_kernel(
    const int* __restrict__ row_ptr, const uint2* __restrict__ sorted_cv,
    const float* __restrict__ embeds, float* __restrict__ out, int n_rows)
{
    const int lane = threadIdx.x & 63;
    const int wid = (blockIdx.x * blockDim.x + threadIdx.x) >> 6;
    const int n_waves = (gridDim.x * blockDim.x) >> 6;

    for (int r = wid; r < n_rows; r += n_waves) {
        const int start = row_ptr[r];
        const int end   = row_ptr[r + 1];
        float2 acc = {0.f, 0.f};
        for (int j = start; j < end; ++j) {
            uint2 cv = sorted_cv[j];
            const float2 e = *reinterpret_cast<const float2*>(&embeds[(size_t)cv.x * D_FEAT + lane * 2]);
            const float v = __uint_as_float(cv.y);
            acc.x += v * e.x;
            acc.y += v * e.y;
        }
        *reinterpret_cast<float2*>(&out[(size_t)r * D_FEAT + lane * 2]) = acc;
    }
}

extern "C" void kernel_launch(void* const* d_in, const int* in_sizes, int n_in,
                              void* d_out, int out_size, void* d_ws, size_t ws_size,
                              hipStream_t stream) {
    const int*   row    = (const int*)d_in[0];
    const int*   col    = (const int*)d_in[1];
    const float* vals   = (const float*)d_in[2];
    const float* embeds = (const float*)d_in[3];
    float*       out    = (float*)d_out;

    const int n_edges = in_sizes[0];
    const int n_nodes = in_sizes[3] / D_FEAT;
    const int nchunks = (n_nodes + SCAN_CHUNK - 1) / SCAN_CHUNK;
    const int nb = (n_nodes + TILE_ROWS - 1) >> BUCKET_SHIFT;

    // padded bucket stride: avg + 25% + 256 (>=16 sigma for Binomial bucket sizes)
    const int avg = n_edges / (nb > 0 ? nb : 1);
    const int cap_b = avg + avg / 4 + 256;

    char* base = (char*)d_ws;

    // padded layout (no hist/scan)
    size_t offP = 0;
    uint2* tmpP           = (uint2*)(base + offP);             offP += ((size_t)nb * cap_b * 8 + 255) & ~(size_t)255;
    unsigned short* emb16P = (unsigned short*)(base + offP);   offP += ((size_t)n_nodes * D_FEAT * 2 + 255) & ~(size_t)255;
    int* bptrP            = (int*)(base + offP);               offP += (size_t)(nb + 1) * 4;
    int* bfillP           = (int*)(base + offP);               offP += (size_t)(nb + 1) * 4;

    // scanned layout (exact tmp)
    size_t offS = 0;
    uint2* tmpS           = (uint2*)(base + offS);             offS += ((size_t)n_edges * 8 + 255) & ~(size_t)255;
    unsigned short* emb16S = (unsigned short*)(base + offS);   offS += ((size_t)n_nodes * D_FEAT * 2 + 255) & ~(size_t)255;
    int* bcntS            = (int*)(base + offS);               offS += (size_t)(nb + 1) * 4;
    int* bptrS            = (int*)(base + offS);               offS += (size_t)(nb + 1) * 4;
    int* bfillS           = (int*)(base + offS);               offS += (size_t)(nb + 1) * 4;

    const bool common_ok = (nb <= 1023) && (n_nodes < (1 << 17));
    const bool padded_ok  = common_ok && (offP <= ws_size);
    const bool scanned_ok = common_ok && (offS <= ws_size);

    if (!padded_ok && !scanned_ok) {
        // round-2 fallback layout
        size_t off2 = 0;
        uint2* s_cv = (uint2*)(base + off2); off2 += (size_t)n_edges * 8;
        int* rc  = (int*)(base + off2); off2 += (size_t)n_nodes * 4;
        int* rf  = (int*)(base + off2); off2 += (size_t)n_nodes * 4;
        int* rp  = (int*)(base + off2); off2 += (size_t)(n_nodes + 1) * 4;
        int* cs  = (int*)(base + off2); off2 += (size_t)nchunks * 4;
        if (off2 > ws_size) {
            hipMemsetAsync(d_out, 0, (size_t)out_size * sizeof(float), stream);
            spmm_atomic_kernel<<<2048, 256, 0, stream>>>(row, col, vals, embeds, out, n_edges);
            return;
        }
        hipMemsetAsync(rc, 0, (size_t)n_nodes * 2 * sizeof(int), stream);
        hist_kernel<<<2048, 256, 0, stream>>>(row, rc, n_edges);
        scan1_kernel<<<nchunks, SCAN_BLOCK, 0, stream>>>(rc, rp, cs, n_nodes);
        scan2_kernel<<<1, 64, 0, stream>>>(cs, nchunks);
        scan3_kernel<<<(n_nodes + 256) / 256, 256, 0, stream>>>(rp, cs, n_nodes, n_edges);
        scatter_kernel<<<2048, 256, 0, stream>>>(row, col, vals, rp, rf, s_cv, n_edges);
        spmm_csr_kernel<<<4096, 256, 0, stream>>>(rp, s_cv, embeds, out, n_nodes);
        return;
    }

    uint2* tmp;
    unsigned short* embeds16;
    int *bptr, *bfill;

    const int part_blocks = (n_edges + PART_TILE - 1) / PART_TILE;

    if (padded_ok) {
        tmp = tmpP; embeds16 = emb16P; bptr = bptrP; bfill = bfillP;
        bucket_init_padded_kernel<<<(nb + 255) / 256, 256, 0, stream>>>(bptr, bfill, nb, cap_b);
    } else {
        tmp = tmpS; embeds16 = emb16S; bptr = bptrS; bfill = bfillS;
        hipMemsetAsync(bcntS, 0, (size_t)(nb + 1) * sizeof(int), stream);
        bucket_hist_kernel<<<512, 256, 0, stream>>>(row, bcntS, n_edges, nb);
        bucket_scan_kernel<<<1, 1024, 0, stream>>>(bcntS, bptr, bfill, nb);
    }

    partition_kernel<<<part_blocks, 256, 0, stream>>>(row, col, vals, bfill, tmp, n_edges, nb);

    const int n4 = n_nodes * D_FEAT / 4;
    convert_kernel<<<4096, 256, 0, stream>>>(embeds, embeds16, n4);

    spmm_bucket_sorted_kernel<<<nb, 1024, 0, stream>>>(tmp, bptr, bfill, embeds16, out, n_nodes);
}